// Round 1
// baseline (535.398 us; speedup 1.0000x reference)
//
#include <hip/hip_runtime.h>
#include <stdint.h>

#define NROWS 2048
#define NCOLS 50257
#define SCALE 30.0f

// Kernel 1: one block per row. Sum exp(30*x) over the row, fetch the target
// logit, emit per-row loss term L_i into ws[row].
__global__ __launch_bounds__(256) void amsoftmax_row_kernel(
    const float* __restrict__ score,
    const int* __restrict__ labels,
    float* __restrict__ row_loss) {
    const int row = blockIdx.x;
    const int tid = threadIdx.x;
    const float* __restrict__ r = score + (size_t)row * NCOLS;

    const int lab = labels[row];
    const float target = r[lab];
    const float margin = lab ? 0.4f : 0.1f;
    const float num = SCALE * (target - margin);

    // Row base is only 4B-aligned (NCOLS odd). Peel to 16B alignment, then float4.
    const uintptr_t addr = (uintptr_t)r;
    const int mis = (int)(((16u - (addr & 15u)) & 15u) >> 2);  // leading scalars

    float acc = 0.0f;
    for (int j = tid; j < mis; j += 256) {
        acc += __expf(SCALE * r[j]);
    }
    const int nvec = (NCOLS - mis) >> 2;
    const float4* __restrict__ rv = (const float4*)(r + mis);
    for (int j = tid; j < nvec; j += 256) {
        float4 v = rv[j];
        acc += __expf(SCALE * v.x);
        acc += __expf(SCALE * v.y);
        acc += __expf(SCALE * v.z);
        acc += __expf(SCALE * v.w);
    }
    for (int j = mis + (nvec << 2) + tid; j < NCOLS; j += 256) {
        acc += __expf(SCALE * r[j]);
    }

    // Wave (64-lane) butterfly reduce, then LDS across the 4 waves.
    for (int off = 32; off > 0; off >>= 1) acc += __shfl_down(acc, off);
    __shared__ float wsum[4];
    if ((tid & 63) == 0) wsum[tid >> 6] = acc;
    __syncthreads();
    if (tid == 0) {
        const float total = wsum[0] + wsum[1] + wsum[2] + wsum[3];
        const float excl = total - __expf(SCALE * target);
        const float denom = __expf(num) + excl;
        row_loss[row] = num - __logf(denom);
    }
}

// Kernel 2: single block reduces the 2048 per-row losses to -mean.
__global__ __launch_bounds__(256) void amsoftmax_reduce_kernel(
    const float* __restrict__ row_loss,
    float* __restrict__ out) {
    const int tid = threadIdx.x;
    float acc = 0.0f;
    for (int i = tid; i < NROWS; i += 256) acc += row_loss[i];
    for (int off = 32; off > 0; off >>= 1) acc += __shfl_down(acc, off);
    __shared__ float wsum[4];
    if ((tid & 63) == 0) wsum[tid >> 6] = acc;
    __syncthreads();
    if (tid == 0) {
        const float total = wsum[0] + wsum[1] + wsum[2] + wsum[3];
        out[0] = -total / (float)NROWS;
    }
}

extern "C" void kernel_launch(void* const* d_in, const int* in_sizes, int n_in,
                              void* d_out, int out_size, void* d_ws, size_t ws_size,
                              hipStream_t stream) {
    const float* score = (const float*)d_in[0];
    const int* labels = (const int*)d_in[1];
    float* out = (float*)d_out;
    float* row_loss = (float*)d_ws;  // NROWS floats, fully overwritten each call

    amsoftmax_row_kernel<<<NROWS, 256, 0, stream>>>(score, labels, row_loss);
    amsoftmax_reduce_kernel<<<1, 256, 0, stream>>>(row_loss, out);
}